// Round 14
// baseline (140.170 us; speedup 1.0000x reference)
//
#include <hip/hip_runtime.h>
#include <hip/hip_bf16.h>
#include <stdint.h>

#define NTOK 8192
#define DIM  1024
#define RD   128
#define NEXP 64
#define TOPK 8
#define MAXT 4096
#define NHB  32    // histogram blocks (256 tokens each)
#define JM   32    // gemm j-range at M=64 (covers 2048 tokens/expert)

// d_out element offsets (f32 elements): output | weights | idx
#define W_OFF (NTOK * RD)            // 1048576
#define I_OFF (W_OFF + NTOK * TOPK)  // 1114112

// ws byte offsets
#define CNT_OFF  0
#define LIST_OFF 1024
#define GC_OFF   (LIST_OFF + NEXP * MAXT * 4)   // 1,049,600
#define NT_OFF   2360320
#define XB_OFF   (NT_OFF + (size_t)NEXP * RD * DIM * 2)    // 19,137,536
#define PW_OFF   (XB_OFF + (size_t)NTOK * DIM * 2)         // 35,914,752
#define PW_END   (PW_OFF + (size_t)NTOK * TOPK * RD * 2)   // 52,691,968
// use_pw layout: sp f64 [4][NTOK][NEXP] lives in the PW region (exact 16MB
// fit) during score/topk; pw bf16 partials overwrite it in gemm (disjoint
// lifetimes). nT owns NT region -> nt_cast is independent and is FUSED into
// the score dispatch (blocks 512..2559) to fill score's latency bubbles.
// Fallback (!use_pw): r12 layout — sp at NT, sequential nt_cast, atomics.

using bh8 = __attribute__((ext_vector_type(8))) short;
using fx4 = __attribute__((ext_vector_type(4))) float;
using dx2 = __attribute__((ext_vector_type(2))) double;
using dx4 = __attribute__((ext_vector_type(4))) double;

__device__ inline unsigned short f2bf(float f) {
    union { __hip_bfloat16 h; unsigned short u; } v;
    v.h = __float2bfloat16(f);
    return v.u;
}

// ---------------------------------------------------------------------------
// nt_cast device body: neurons [e][d][r] f32 -> nT [e][r][d] bf16
// ---------------------------------------------------------------------------
__device__ inline void nt_body(int bx, int tid, char* smemraw,
                               const float* __restrict__ nr,
                               __hip_bfloat16* __restrict__ nT) {
    float (*t)[65] = (float (*)[65])smemraw;   // 16,640 B
    int e   = bx >> 5;
    int sub = bx & 31;
    int d0  = (sub >> 1) * 64;
    int r0  = (sub & 1) * 64;
    int dd  = tid >> 2;
    int rr4 = (tid & 3) * 16;
    const float* src = nr + ((size_t)e * DIM + d0 + dd) * RD + r0 + rr4;
    fx4 v[4];
    #pragma unroll
    for (int u = 0; u < 4; ++u) v[u] = ((const fx4*)src)[u];
    #pragma unroll
    for (int u = 0; u < 4; ++u)
        #pragma unroll
        for (int c = 0; c < 4; ++c) t[dd][rr4 + u * 4 + c] = v[u][c];
    __syncthreads();
    int rr  = tid >> 2;
    int dd4 = (tid & 3) * 16;
    union { unsigned short u[16]; uint4 q[2]; } o;
    #pragma unroll
    for (int i = 0; i < 16; ++i) o.u[i] = f2bf(t[dd4 + i][rr]);
    __hip_bfloat16* dst = nT + ((size_t)e * RD + r0 + rr) * DIM + d0 + dd4;
    ((uint4*)dst)[0] = o.q[0];
    ((uint4*)dst)[1] = o.q[1];
}

// ---------------------------------------------------------------------------
// score device body (r12-proven): fp64 scores, D-split x4 -> sp[ds][T][n].
// f64 X+W LDS tiles, reg-prefetch, fused x_cast. Bit-identical sp to r12.
// ---------------------------------------------------------------------------
__device__ inline void score_body(int bx, int tid, char* smem,
                                  const float* __restrict__ x,
                                  const float* __restrict__ rw,
                                  double* __restrict__ sp,
                                  unsigned short* __restrict__ xb) {
    double (*Xs)[66] = (double (*)[66])smem;
    double (*Ws)[66] = (double (*)[66])(smem + 64 * 66 * 8);
    double (*Ssc)[65] = (double (*)[65])smem;   // alias after compute

    int ds  = bx & 3;
    int tb  = (bx >> 2) * 64;
    int ni  = tid & 15;        // experts: ni + 16*j
    int ti  = tid >> 4;        // tokens:  ti*4 + i

    double acc[4][4];
    #pragma unroll
    for (int i = 0; i < 4; ++i)
        #pragma unroll
        for (int j = 0; j < 4; ++j) acc[i][j] = 0.0;

    int srow = tid >> 2;          // 0..63
    int scol = (tid & 3) * 16;    // 0,16,32,48

    fx4 xv[4], wv[4];
    {   // preload chunk 0
        const float* xs = x  + (size_t)(tb + srow) * DIM + ds * 256 + scol;
        const float* ws = rw + (size_t)srow        * DIM + ds * 256 + scol;
        #pragma unroll
        for (int u = 0; u < 4; ++u) { xv[u] = ((const fx4*)xs)[u]; wv[u] = ((const fx4*)ws)[u]; }
    }

    for (int c = 0; c < 4; ++c) {
        __syncthreads();   // prior dq-compute done reading LDS
        #pragma unroll
        for (int u = 0; u < 4; ++u) {
            #pragma unroll
            for (int k = 0; k < 4; k += 2) {
                dx2 xd; xd[0] = (double)xv[u][k]; xd[1] = (double)xv[u][k + 1];
                *(dx2*)&Xs[srow][scol + u * 4 + k] = xd;
                dx2 wd; wd[0] = (double)wv[u][k]; wd[1] = (double)wv[u][k + 1];
                *(dx2*)&Ws[srow][scol + u * 4 + k] = wd;
            }
        }
        // fused x_cast
        {
            bh8 o0, o1;
            #pragma unroll
            for (int c2 = 0; c2 < 4; ++c2) {
                o0[c2]     = (short)f2bf(xv[0][c2]);
                o0[4 + c2] = (short)f2bf(xv[1][c2]);
                o1[c2]     = (short)f2bf(xv[2][c2]);
                o1[4 + c2] = (short)f2bf(xv[3][c2]);
            }
            unsigned short* xd = xb + (size_t)(tb + srow) * DIM + ds * 256 + c * 64 + scol;
            *(bh8*)xd = o0;
            *(bh8*)(xd + 8) = o1;
        }
        __syncthreads();
        if (c < 3) {   // prefetch next chunk
            int d0 = ds * 256 + (c + 1) * 64;
            const float* xs = x  + (size_t)(tb + srow) * DIM + d0 + scol;
            const float* ws = rw + (size_t)srow        * DIM + d0 + scol;
            #pragma unroll
            for (int u = 0; u < 4; ++u) { xv[u] = ((const fx4*)xs)[u]; wv[u] = ((const fx4*)ws)[u]; }
        }
        for (int dq = 0; dq < 64; dq += 4) {
            dx4 xa[4], wb[4];
            #pragma unroll
            for (int i = 0; i < 4; ++i) xa[i] = *(const dx4*)&Xs[ti * 4 + i][dq];
            #pragma unroll
            for (int j = 0; j < 4; ++j) wb[j] = *(const dx4*)&Ws[ni + 16 * j][dq];
            #pragma unroll
            for (int i = 0; i < 4; ++i)
                #pragma unroll
                for (int j = 0; j < 4; ++j)
                    acc[i][j] += xa[i][0] * wb[j][0]
                               + xa[i][1] * wb[j][1]
                               + xa[i][2] * wb[j][2]
                               + xa[i][3] * wb[j][3];
        }
    }
    __syncthreads();
    #pragma unroll
    for (int i = 0; i < 4; ++i)
        #pragma unroll
        for (int j = 0; j < 4; ++j) Ssc[ti * 4 + i][ni + 16 * j] = acc[i][j];
    __syncthreads();

    int t  = tid >> 2;
    int n0 = (tid & 3) * 16;
    double* dst = sp + ((size_t)ds * NTOK + tb + t) * NEXP + n0;
    #pragma unroll
    for (int k = 0; k < 16; ++k) dst[k] = Ssc[t][n0 + k];
}

// ---------------------------------------------------------------------------
// Kernel A (use_pw path): fused score (blocks 0..511) + nt_cast (512..2559).
// nt's memory-bound waves fill score's latency bubbles.
// ---------------------------------------------------------------------------
__global__ __launch_bounds__(256) void score_nt_k(const float* __restrict__ x,
                                                  const float* __restrict__ rw,
                                                  const float* __restrict__ nr,
                                                  double* __restrict__ sp,
                                                  __hip_bfloat16* __restrict__ nT,
                                                  unsigned short* __restrict__ xb) {
    __shared__ __align__(16) char smem[2 * 64 * 66 * 8];   // 67,584 B
    int tid = threadIdx.x;
    if (blockIdx.x < 512) score_body(blockIdx.x, tid, smem, x, rw, sp, xb);
    else                  nt_body(blockIdx.x - 512, tid, smem, nr, nT);
}

// Standalone kernels for the !use_pw fallback (r12 ordering)
__global__ __launch_bounds__(256) void score_k(const float* __restrict__ x,
                                               const float* __restrict__ rw,
                                               double* __restrict__ sp,
                                               unsigned short* __restrict__ xb) {
    __shared__ __align__(16) char smem[2 * 64 * 66 * 8];
    score_body(blockIdx.x, threadIdx.x, smem, x, rw, sp, xb);
}
__global__ __launch_bounds__(256) void nt_cast(const float* __restrict__ nr,
                                               __hip_bfloat16* __restrict__ nT) {
    __shared__ __align__(16) char smem[64 * 65 * 4];
    nt_body(blockIdx.x, threadIdx.x, smem, nr, nT);
}

// ---------------------------------------------------------------------------
// Kernel 2: wave-per-token f64 top-8 + softmax. Plain stores only.
// ---------------------------------------------------------------------------
__global__ __launch_bounds__(256) void topk_k(const double* __restrict__ sp,
                                              float* __restrict__ out) {
    int wave = threadIdx.x >> 6, lane = threadIdx.x & 63;
    int T = blockIdx.x * 4 + wave;

    const double* base = sp + (size_t)T * NEXP + lane;
    const size_t SL = (size_t)NTOK * NEXP;
    double s = base[0] + base[SL] + base[2 * SL] + base[3 * SL];

    double vals[TOPK]; int idxs[TOPK];
    double cur = s;
    #pragma unroll
    for (int p = 0; p < TOPK; ++p) {
        double v = cur; int i = lane;
        #pragma unroll
        for (int off = 32; off > 0; off >>= 1) {
            double ov = __shfl_xor(v, off, 64);
            int    oi = __shfl_xor(i, off, 64);
            if (ov > v || (ov == v && oi < i)) { v = ov; i = oi; }
        }
        vals[p] = v; idxs[p] = i;
        if (lane == i) cur = -1e300;
    }

    double m = vals[0], sum = 0.0, ex[TOPK];
    #pragma unroll
    for (int p = 0; p < TOPK; ++p) { ex[p] = exp(vals[p] - m); sum += ex[p]; }
    double inv = 1.0 / sum;

    if (lane < TOPK) {
        int p = lane;
        out[W_OFF + T * TOPK + p] = (float)(ex[p] * inv);
        out[I_OFF + T * TOPK + p] = (float)idxs[p];
    }
}

// ---------------------------------------------------------------------------
// Kernel 3: per-block expert histogram (LDS atomics only)
// ---------------------------------------------------------------------------
__global__ __launch_bounds__(256) void hist_k(const float* __restrict__ out,
                                              int* __restrict__ gcnt) {
    __shared__ int lh[NEXP];
    int tid = threadIdx.x;
    if (tid < NEXP) lh[tid] = 0;
    __syncthreads();
    int T = blockIdx.x * 256 + tid;
    const fx4* ip = (const fx4*)(out + I_OFF + (size_t)T * TOPK);
    fx4 a = ip[0], b = ip[1];
    #pragma unroll
    for (int p = 0; p < 4; ++p) { atomicAdd(&lh[(int)a[p]], 1); atomicAdd(&lh[(int)b[p]], 1); }
    __syncthreads();
    if (tid < NEXP) gcnt[blockIdx.x * NEXP + tid] = lh[tid];
}

// ---------------------------------------------------------------------------
// Kernel 4: scatter entries into lists (scan folded in: each block computes
// its own prefix from gcnt; block 0 writes cnt totals)
// ---------------------------------------------------------------------------
__global__ __launch_bounds__(256) void scatter_k(const float* __restrict__ out,
                                                 const int* __restrict__ gcnt,
                                                 int* __restrict__ lists,
                                                 int* __restrict__ cnt) {
    __shared__ int lh[NEXP];
    __shared__ int bo[NEXP];
    int tid = threadIdx.x;
    if (tid < NEXP) {
        lh[tid] = 0;
        int s = 0, tot = 0;
        #pragma unroll
        for (int b = 0; b < NHB; ++b) {
            int g = gcnt[b * NEXP + tid];
            if (b < (int)blockIdx.x) s += g;
            tot += g;
        }
        bo[tid] = tid * MAXT + s;
        if (blockIdx.x == 0) cnt[tid] = tot;
    }
    __syncthreads();
    int T = blockIdx.x * 256 + tid;
    const fx4* ip = (const fx4*)(out + I_OFF + (size_t)T * TOPK);
    fx4 a = ip[0], b = ip[1];
    int ev[TOPK] = {(int)a[0], (int)a[1], (int)a[2], (int)a[3],
                    (int)b[0], (int)b[1], (int)b[2], (int)b[3]};
    #pragma unroll
    for (int p = 0; p < TOPK; ++p) {
        int e = ev[p];
        int pos = atomicAdd(&lh[e], 1);
        lists[bo[e] + pos] = (T << 3) | p;
    }
}

// ---------------------------------------------------------------------------
// Kernel 5: grouped gather-GEMM, tile 64 tok x 128 R, BK=64, depth-2
// counted-vmcnt pipeline (r12 structure, best known).
// ---------------------------------------------------------------------------
__global__ __launch_bounds__(256) void gemm_k(const unsigned short* __restrict__ xb,
                                              const unsigned short* __restrict__ nTb,
                                              const int* __restrict__ cnt,
                                              const int* __restrict__ lists,
                                              float* __restrict__ outf,
                                              unsigned short* __restrict__ pw,
                                              int use_pw) {
    int e = blockIdx.x & 63;
    int j = blockIdx.x >> 6;       // 0..JM-1
    int ce = cnt[e];
    int base = j * 64;
    if (base >= ce) return;

    __shared__ unsigned short As[2][64 * 64];    // 16 KB
    __shared__ unsigned short Bs[2][128 * 64];   // 32 KB
    __shared__ int   plist[64];
    __shared__ float wl[64];

    int tid = threadIdx.x;
    int wave = tid >> 6, lane = tid & 63;
    if (tid < 64) {
        int idx = base + tid;
        int p = (idx < ce) ? lists[e * MAXT + idx] : -1;
        plist[tid] = p;
        wl[tid] = (p >= 0) ? outf[W_OFF + p] : 0.0f;
    }
    __syncthreads();

    fx4 acc[2][4];
    #pragma unroll
    for (int a = 0; a < 2; ++a)
        #pragma unroll
        for (int b = 0; b < 4; ++b) acc[a][b] = (fx4){0.f, 0.f, 0.f, 0.f};

    unsigned soff = 16u * (unsigned)((lane & 7) ^ (lane >> 3));
    const char* asrc[2];
    const char* bsrc[4];
    const char* xbb = (const char*)xb;
    const char* ntb = (const char*)(nTb + (size_t)e * RD * DIM);
    #pragma unroll
    for (int c = 0; c < 2; ++c) {
        int row = (wave * 2 + c) * 8 + (lane >> 3);   // 0..63
        int p = plist[row];
        int tok = (p < 0) ? 0 : (p >> 3);
        asrc[c] = xbb + (size_t)tok * (DIM * 2) + soff;
    }
    #pragma unroll
    for (int c = 0; c < 4; ++c) {
        int row = (wave * 4 + c) * 8 + (lane >> 3);   // 0..127
        bsrc[c] = ntb + (size_t)row * (DIM * 2) + soff;
    }

    int wm = (wave >> 1) * 32, wn = (wave & 1) * 64;
    int lr = lane & 15, lk = (lane >> 4) * 8;
    int lg = lane >> 4;

    auto stage = [&](int kt, int bsel) {
        int db = kt * 128;
        #pragma unroll
        for (int c = 0; c < 2; ++c) {
            __builtin_amdgcn_global_load_lds(
                (const __attribute__((address_space(1))) void*)(asrc[c] + db),
                (__attribute__((address_space(3))) void*)(&As[bsel][(wave * 2 + c) * 512]),
                16, 0, 0);
        }
        #pragma unroll
        for (int c = 0; c < 4; ++c) {
            __builtin_amdgcn_global_load_lds(
                (const __attribute__((address_space(1))) void*)(bsrc[c] + db),
                (__attribute__((address_space(3))) void*)(&Bs[bsel][(wave * 4 + c) * 512]),
                16, 0, 0);
        }
    };

    auto mfma_tile = [&](int bsel) {
        const char* Ab = (const char*)As[bsel];
        const char* Bb = (const char*)Bs[bsel];
        #pragma unroll
        for (int kk = 0; kk < 2; ++kk) {
            int k0 = kk * 32;
            bh8 av[2], bv[4];
            #pragma unroll
            for (int mf = 0; mf < 2; ++mf) {
                unsigned row = (unsigned)(wm + mf * 16 + lr);
                unsigned bo = row * 128 + (unsigned)(k0 + lk) * 2;
                bo ^= (row & 7) << 4;
                av[mf] = *(const bh8*)(Ab + bo);
            }
            #pragma unroll
            for (int nf = 0; nf < 4; ++nf) {
                unsigned row = (unsigned)(wn + nf * 16 + lr);
                unsigned bo = row * 128 + (unsigned)(k0 + lk) * 2;
                bo ^= (row & 7) << 4;
                bv[nf] = *(const bh8*)(Bb + bo);
            }
            #pragma unroll
            for (int mf = 0; mf < 2; ++mf)
                #pragma unroll
                for (int nf = 0; nf < 4; ++nf)
                    acc[mf][nf] = __builtin_amdgcn_mfma_f32_16x16x32_bf16(av[mf], bv[nf], acc[mf][nf], 0, 0, 0);
        }
    };

    // prologue: 2 tiles in flight (12 loads/lane)
    stage(0, 0);
    stage(1, 1);

    for (int kt = 0; kt < 15; ++kt) {
        int bsel = kt & 1;
        asm volatile("s_waitcnt vmcnt(6)" ::: "memory");
        __builtin_amdgcn_s_barrier();
        asm volatile("" ::: "memory");
        mfma_tile(bsel);
        asm volatile("s_waitcnt lgkmcnt(0)" ::: "memory");
        __builtin_amdgcn_s_barrier();
        asm volatile("" ::: "memory");
        if (kt < 14) stage(kt + 2, bsel);
    }
    asm volatile("s_waitcnt vmcnt(0)" ::: "memory");
    __builtin_amdgcn_s_barrier();
    asm volatile("" ::: "memory");
    mfma_tile(1);

    if (use_pw) {
        #pragma unroll
        for (int mf = 0; mf < 2; ++mf) {
            #pragma unroll
            for (int rg = 0; rg < 4; ++rg) {
                int row = wm + mf * 16 + lg * 4 + rg;
                int p = plist[row];
                if (p < 0) continue;
                float wg = wl[row];
                #pragma unroll
                for (int nf = 0; nf < 4; ++nf) {
                    int r = wn + nf * 16 + lr;
                    pw[(size_t)p * RD + r] = f2bf(acc[mf][nf][rg] * wg);
                }
            }
        }
    } else {
        #pragma unroll
        for (int mf = 0; mf < 2; ++mf) {
            #pragma unroll
            for (int rg = 0; rg < 4; ++rg) {
                int row = wm + mf * 16 + lg * 4 + rg;
                int p = plist[row];
                if (p < 0) continue;
                float wg = wl[row];
                int t = p >> 3;
                #pragma unroll
                for (int nf = 0; nf < 4; ++nf) {
                    int r = wn + nf * 16 + lr;
                    atomicAdd(&outf[(size_t)t * RD + r], acc[mf][nf][rg] * wg);
                }
            }
        }
    }
}

// ---------------------------------------------------------------------------
// Kernel 6: y[t][r] = sum_k pw[(t*8+k)][r]   (pw path only; coalesced)
// ---------------------------------------------------------------------------
__global__ __launch_bounds__(256) void reduce_k(const unsigned short* __restrict__ pw,
                                                float* __restrict__ y) {
    int gid = blockIdx.x * 256 + threadIdx.x;
    int t = gid >> 7, r = gid & 127;
    float s = 0.f;
    #pragma unroll
    for (int k = 0; k < TOPK; ++k) {
        unsigned int w = ((unsigned int)pw[((size_t)t * TOPK + k) * RD + r]) << 16;
        s += __uint_as_float(w);
    }
    y[gid] = s;
}

// ---------------------------------------------------------------------------
extern "C" void kernel_launch(void* const* d_in, const int* in_sizes, int n_in,
                              void* d_out, int out_size, void* d_ws, size_t ws_size,
                              hipStream_t stream) {
    const float* x  = (const float*)d_in[0];
    const float* rw = (const float*)d_in[1];
    const float* nr = (const float*)d_in[2];
    float* out = (float*)d_out;
    char* ws = (char*)d_ws;
    int*    cnt   = (int*)(ws + CNT_OFF);
    int*    lists = (int*)(ws + LIST_OFF);
    int*    gcnt  = (int*)(ws + GC_OFF);
    __hip_bfloat16* nT = (__hip_bfloat16*)(ws + NT_OFF);
    unsigned short* xbu = (unsigned short*)(ws + XB_OFF);
    unsigned short* pw  = (unsigned short*)(ws + PW_OFF);

    const int use_pw = (ws_size >= (size_t)PW_END) ? 1 : 0;

    if (use_pw) {
        double* sp = (double*)(ws + PW_OFF);   // sp lives in PW region (disjoint lifetime)
        score_nt_k<<<512 + 2048, 256, 0, stream>>>(x, rw, nr, sp, nT, xbu);
        topk_k<<<NTOK / 4, 256, 0, stream>>>(sp, out);
        hist_k<<<NHB, 256, 0, stream>>>(out, gcnt);
        scatter_k<<<NHB, 256, 0, stream>>>(out, gcnt, lists, cnt);
        gemm_k<<<NEXP * JM, 256, 0, stream>>>(xbu, (const unsigned short*)nT, cnt, lists, out, pw, 1);
        reduce_k<<<(NTOK * RD) / 256, 256, 0, stream>>>(pw, out);
    } else {
        double* sp = (double*)(ws + NT_OFF);   // r12 fallback layout
        hipMemsetAsync(out, 0, (size_t)NTOK * RD * sizeof(float), stream);
        score_k<<<512, 256, 0, stream>>>(x, rw, sp, xbu);
        topk_k<<<NTOK / 4, 256, 0, stream>>>(sp, out);
        nt_cast<<<2048, 256, 0, stream>>>(nr, nT);
        hist_k<<<NHB, 256, 0, stream>>>(out, gcnt);
        scatter_k<<<NHB, 256, 0, stream>>>(out, gcnt, lists, cnt);
        gemm_k<<<NEXP * JM, 256, 0, stream>>>(xbu, (const unsigned short*)nT, cnt, lists, out, pw, 0);
    }
}

// Round 15
// 113.998 us; speedup vs baseline: 1.2296x; 1.2296x over previous
//
#include <hip/hip_runtime.h>
#include <hip/hip_bf16.h>
#include <stdint.h>

#define NTOK 8192
#define DIM  1024
#define RD   128
#define NEXP 64
#define TOPK 8
#define MAXT 4096
#define NHB  32    // histogram blocks (256 tokens each)
#define JM   32    // gemm j-range at M=64 (covers 2048 tokens/expert)

// d_out element offsets (f32 elements): output | weights | idx
#define W_OFF (NTOK * RD)            // 1048576
#define I_OFF (W_OFF + NTOK * TOPK)  // 1114112

// ws byte offsets
#define CNT_OFF  0
#define LIST_OFF 1024
#define GC_OFF   (LIST_OFF + NEXP * MAXT * 4)   // 1,049,600
#define NT_OFF   2360320
#define XB_OFF   (NT_OFF + (size_t)NEXP * RD * DIM * 2)    // 19,137,536
#define PW_OFF   (XB_OFF + (size_t)NTOK * DIM * 2)         // 35,914,752
#define PW_END   (PW_OFF + (size_t)NTOK * TOPK * RD * 2)   // 52,691,968
// NT region (16 MB) time-shared: sp f64 [4][NTOK][NEXP] during score/topk,
// then nT bf16 (nt_cast runs AFTER topk_k). XB: xb bf16 (fused x_cast).
// PW region (16 MB, bf16 partials) used ONLY if ws_size >= PW_END.

using bh8 = __attribute__((ext_vector_type(8))) short;
using fx4 = __attribute__((ext_vector_type(4))) float;
using dx2 = __attribute__((ext_vector_type(2))) double;
using dx4 = __attribute__((ext_vector_type(4))) double;

__device__ inline unsigned short f2bf(float f) {
    union { __hip_bfloat16 h; unsigned short u; } v;
    v.h = __float2bfloat16(f);
    return v.u;
}

// ---------------------------------------------------------------------------
// Kernel 0: neurons [e][d][r] f32  ->  nT [e][r][d] bf16  (B^T for MFMA)
// ---------------------------------------------------------------------------
__global__ __launch_bounds__(256) void nt_cast(const float* __restrict__ nr,
                                               __hip_bfloat16* __restrict__ nT) {
    int bx  = blockIdx.x;
    int e   = bx >> 5;
    int sub = bx & 31;
    int d0  = (sub >> 1) * 64;
    int r0  = (sub & 1) * 64;
    __shared__ float t[64][65];
    int tid = threadIdx.x;
    int dd  = tid >> 2;
    int rr4 = (tid & 3) * 16;
    const float* src = nr + ((size_t)e * DIM + d0 + dd) * RD + r0 + rr4;
    fx4 v[4];
    #pragma unroll
    for (int u = 0; u < 4; ++u) v[u] = ((const fx4*)src)[u];
    #pragma unroll
    for (int u = 0; u < 4; ++u)
        #pragma unroll
        for (int c = 0; c < 4; ++c) t[dd][rr4 + u * 4 + c] = v[u][c];
    __syncthreads();
    int rr  = tid >> 2;
    int dd4 = (tid & 3) * 16;
    union { unsigned short u[16]; uint4 q[2]; } o;
    #pragma unroll
    for (int i = 0; i < 16; ++i) o.u[i] = f2bf(t[dd4 + i][rr]);
    __hip_bfloat16* dst = nT + ((size_t)e * RD + r0 + rr) * DIM + d0 + dd4;
    ((uint4*)dst)[0] = o.q[0];
    ((uint4*)dst)[1] = o.q[1];
}

// ---------------------------------------------------------------------------
// Kernel 1: fp64 partial router scores, D-split x4 -> sp[ds][T][n]
// v4: 32-token tiles (Xs[32][66]+Ws[64][66] f64 = 50.7 KB -> 3 blocks/CU,
// grid 1024, 12 waves/CU for latency cover). Per-score chunk/dq/product
// order identical to r12 -> sp bit-identical. ALSO emits xb (fused x_cast).
// ---------------------------------------------------------------------------
__global__ __launch_bounds__(256) void score_k(const float* __restrict__ x,
                                               const float* __restrict__ rw,
                                               double* __restrict__ sp,
                                               unsigned short* __restrict__ xb) {
    __shared__ __align__(16) char smem[32 * 66 * 8 + 64 * 66 * 8];  // 50,688 B
    double (*Xs)[66] = (double (*)[66])smem;
    double (*Ws)[66] = (double (*)[66])(smem + 32 * 66 * 8);
    double (*Ssc)[65] = (double (*)[65])smem;   // 32x65x8=16,640 <= Xs region

    int tid = threadIdx.x;
    int ds  = blockIdx.x & 3;
    int tb  = (blockIdx.x >> 2) * 32;
    int ni  = tid & 15;        // experts: ni + 16*j
    int ti  = tid >> 4;        // tokens:  ti*2 + i

    double acc[2][4];
    #pragma unroll
    for (int i = 0; i < 2; ++i)
        #pragma unroll
        for (int j = 0; j < 4; ++j) acc[i][j] = 0.0;

    int sxr = tid >> 3;           // X stage row 0..31
    int sxc = (tid & 7) * 8;      // 8 floats
    int swr = tid >> 2;           // W stage row 0..63
    int swc = (tid & 3) * 16;     // 16 floats

    fx4 xv[2], wv[4];
    {   // preload chunk 0
        const float* xs = x  + (size_t)(tb + sxr) * DIM + ds * 256 + sxc;
        const float* ws = rw + (size_t)swr        * DIM + ds * 256 + swc;
        xv[0] = ((const fx4*)xs)[0]; xv[1] = ((const fx4*)xs)[1];
        #pragma unroll
        for (int u = 0; u < 4; ++u) wv[u] = ((const fx4*)ws)[u];
    }

    for (int c = 0; c < 4; ++c) {
        __syncthreads();   // prior dq-compute done reading LDS
        // stage X (f64) rows 0..31
        #pragma unroll
        for (int u = 0; u < 2; ++u) {
            #pragma unroll
            for (int k = 0; k < 4; k += 2) {
                dx2 xd; xd[0] = (double)xv[u][k]; xd[1] = (double)xv[u][k + 1];
                *(dx2*)&Xs[sxr][sxc + u * 4 + k] = xd;
            }
        }
        // stage W (f64) rows 0..63
        #pragma unroll
        for (int u = 0; u < 4; ++u) {
            #pragma unroll
            for (int k = 0; k < 4; k += 2) {
                dx2 wd; wd[0] = (double)wv[u][k]; wd[1] = (double)wv[u][k + 1];
                *(dx2*)&Ws[swr][swc + u * 4 + k] = wd;
            }
        }
        // fused x_cast: this thread's 8 x-floats -> 16 B store
        {
            bh8 o;
            #pragma unroll
            for (int c2 = 0; c2 < 4; ++c2) {
                o[c2]     = (short)f2bf(xv[0][c2]);
                o[4 + c2] = (short)f2bf(xv[1][c2]);
            }
            *(bh8*)(xb + (size_t)(tb + sxr) * DIM + ds * 256 + c * 64 + sxc) = o;
        }
        __syncthreads();
        if (c < 3) {   // prefetch next chunk (hides under dq-compute)
            int d0 = ds * 256 + (c + 1) * 64;
            const float* xs = x  + (size_t)(tb + sxr) * DIM + d0 + sxc;
            const float* ws = rw + (size_t)swr        * DIM + d0 + swc;
            xv[0] = ((const fx4*)xs)[0]; xv[1] = ((const fx4*)xs)[1];
            #pragma unroll
            for (int u = 0; u < 4; ++u) wv[u] = ((const fx4*)ws)[u];
        }
        for (int dq = 0; dq < 64; dq += 4) {
            dx4 xa[2], wb[4];
            #pragma unroll
            for (int i = 0; i < 2; ++i) xa[i] = *(const dx4*)&Xs[ti * 2 + i][dq];
            #pragma unroll
            for (int j = 0; j < 4; ++j) wb[j] = *(const dx4*)&Ws[ni + 16 * j][dq];
            #pragma unroll
            for (int i = 0; i < 2; ++i)
                #pragma unroll
                for (int j = 0; j < 4; ++j)
                    acc[i][j] += xa[i][0] * wb[j][0]
                               + xa[i][1] * wb[j][1]
                               + xa[i][2] * wb[j][2]
                               + xa[i][3] * wb[j][3];
        }
    }
    __syncthreads();   // done reading Xs/Ws; safe to alias with Ssc
    #pragma unroll
    for (int i = 0; i < 2; ++i)
        #pragma unroll
        for (int j = 0; j < 4; ++j) Ssc[ti * 2 + i][ni + 16 * j] = acc[i][j];
    __syncthreads();

    int t  = tid >> 3;            // 0..31
    int n0 = (tid & 7) * 8;       // 8 doubles
    double* dst = sp + ((size_t)ds * NTOK + tb + t) * NEXP + n0;
    #pragma unroll
    for (int k = 0; k < 8; ++k) dst[k] = Ssc[t][n0 + k];
}

// ---------------------------------------------------------------------------
// Kernel 2: wave-per-token f64 top-8 + softmax. Plain stores only.
// ---------------------------------------------------------------------------
__global__ __launch_bounds__(256) void topk_k(const double* __restrict__ sp,
                                              float* __restrict__ out) {
    int wave = threadIdx.x >> 6, lane = threadIdx.x & 63;
    int T = blockIdx.x * 4 + wave;

    const double* base = sp + (size_t)T * NEXP + lane;
    const size_t SL = (size_t)NTOK * NEXP;
    double s = base[0] + base[SL] + base[2 * SL] + base[3 * SL];

    double vals[TOPK]; int idxs[TOPK];
    double cur = s;
    #pragma unroll
    for (int p = 0; p < TOPK; ++p) {
        double v = cur; int i = lane;
        #pragma unroll
        for (int off = 32; off > 0; off >>= 1) {
            double ov = __shfl_xor(v, off, 64);
            int    oi = __shfl_xor(i, off, 64);
            if (ov > v || (ov == v && oi < i)) { v = ov; i = oi; }
        }
        vals[p] = v; idxs[p] = i;
        if (lane == i) cur = -1e300;
    }

    double m = vals[0], sum = 0.0, ex[TOPK];
    #pragma unroll
    for (int p = 0; p < TOPK; ++p) { ex[p] = exp(vals[p] - m); sum += ex[p]; }
    double inv = 1.0 / sum;

    if (lane < TOPK) {
        int p = lane;
        out[W_OFF + T * TOPK + p] = (float)(ex[p] * inv);
        out[I_OFF + T * TOPK + p] = (float)idxs[p];
    }
}

// ---------------------------------------------------------------------------
// Kernel 3: per-block expert histogram (LDS atomics only)
// ---------------------------------------------------------------------------
__global__ __launch_bounds__(256) void hist_k(const float* __restrict__ out,
                                              int* __restrict__ gcnt) {
    __shared__ int lh[NEXP];
    int tid = threadIdx.x;
    if (tid < NEXP) lh[tid] = 0;
    __syncthreads();
    int T = blockIdx.x * 256 + tid;
    const fx4* ip = (const fx4*)(out + I_OFF + (size_t)T * TOPK);
    fx4 a = ip[0], b = ip[1];
    #pragma unroll
    for (int p = 0; p < 4; ++p) { atomicAdd(&lh[(int)a[p]], 1); atomicAdd(&lh[(int)b[p]], 1); }
    __syncthreads();
    if (tid < NEXP) gcnt[blockIdx.x * NEXP + tid] = lh[tid];
}

// ---------------------------------------------------------------------------
// Kernel 4: scatter entries into lists (scan folded in, r14-validated:
// each block computes its prefix from gcnt; block 0 writes cnt totals)
// ---------------------------------------------------------------------------
__global__ __launch_bounds__(256) void scatter_k(const float* __restrict__ out,
                                                 const int* __restrict__ gcnt,
                                                 int* __restrict__ lists,
                                                 int* __restrict__ cnt) {
    __shared__ int lh[NEXP];
    __shared__ int bo[NEXP];
    int tid = threadIdx.x;
    if (tid < NEXP) {
        lh[tid] = 0;
        int s = 0, tot = 0;
        #pragma unroll
        for (int b = 0; b < NHB; ++b) {
            int g = gcnt[b * NEXP + tid];
            if (b < (int)blockIdx.x) s += g;
            tot += g;
        }
        bo[tid] = tid * MAXT + s;
        if (blockIdx.x == 0) cnt[tid] = tot;
    }
    __syncthreads();
    int T = blockIdx.x * 256 + tid;
    const fx4* ip = (const fx4*)(out + I_OFF + (size_t)T * TOPK);
    fx4 a = ip[0], b = ip[1];
    int ev[TOPK] = {(int)a[0], (int)a[1], (int)a[2], (int)a[3],
                    (int)b[0], (int)b[1], (int)b[2], (int)b[3]};
    #pragma unroll
    for (int p = 0; p < TOPK; ++p) {
        int e = ev[p];
        int pos = atomicAdd(&lh[e], 1);
        lists[bo[e] + pos] = (T << 3) | p;
    }
}

// ---------------------------------------------------------------------------
// Kernel 5: grouped gather-GEMM, tile 64 tok x 128 R, BK=64, depth-2
// counted-vmcnt pipeline (r12 structure, best known).
// ---------------------------------------------------------------------------
__global__ __launch_bounds__(256) void gemm_k(const unsigned short* __restrict__ xb,
                                              const unsigned short* __restrict__ nTb,
                                              const int* __restrict__ cnt,
                                              const int* __restrict__ lists,
                                              float* __restrict__ outf,
                                              unsigned short* __restrict__ pw,
                                              int use_pw) {
    int e = blockIdx.x & 63;
    int j = blockIdx.x >> 6;       // 0..JM-1
    int ce = cnt[e];
    int base = j * 64;
    if (base >= ce) return;

    __shared__ unsigned short As[2][64 * 64];    // 16 KB
    __shared__ unsigned short Bs[2][128 * 64];   // 32 KB
    __shared__ int   plist[64];
    __shared__ float wl[64];

    int tid = threadIdx.x;
    int wave = tid >> 6, lane = tid & 63;
    if (tid < 64) {
        int idx = base + tid;
        int p = (idx < ce) ? lists[e * MAXT + idx] : -1;
        plist[tid] = p;
        wl[tid] = (p >= 0) ? outf[W_OFF + p] : 0.0f;
    }
    __syncthreads();

    fx4 acc[2][4];
    #pragma unroll
    for (int a = 0; a < 2; ++a)
        #pragma unroll
        for (int b = 0; b < 4; ++b) acc[a][b] = (fx4){0.f, 0.f, 0.f, 0.f};

    unsigned soff = 16u * (unsigned)((lane & 7) ^ (lane >> 3));
    const char* asrc[2];
    const char* bsrc[4];
    const char* xbb = (const char*)xb;
    const char* ntb = (const char*)(nTb + (size_t)e * RD * DIM);
    #pragma unroll
    for (int c = 0; c < 2; ++c) {
        int row = (wave * 2 + c) * 8 + (lane >> 3);   // 0..63
        int p = plist[row];
        int tok = (p < 0) ? 0 : (p >> 3);
        asrc[c] = xbb + (size_t)tok * (DIM * 2) + soff;
    }
    #pragma unroll
    for (int c = 0; c < 4; ++c) {
        int row = (wave * 4 + c) * 8 + (lane >> 3);   // 0..127
        bsrc[c] = ntb + (size_t)row * (DIM * 2) + soff;
    }

    int wm = (wave >> 1) * 32, wn = (wave & 1) * 64;
    int lr = lane & 15, lk = (lane >> 4) * 8;
    int lg = lane >> 4;

    auto stage = [&](int kt, int bsel) {
        int db = kt * 128;
        #pragma unroll
        for (int c = 0; c < 2; ++c) {
            __builtin_amdgcn_global_load_lds(
                (const __attribute__((address_space(1))) void*)(asrc[c] + db),
                (__attribute__((address_space(3))) void*)(&As[bsel][(wave * 2 + c) * 512]),
                16, 0, 0);
        }
        #pragma unroll
        for (int c = 0; c < 4; ++c) {
            __builtin_amdgcn_global_load_lds(
                (const __attribute__((address_space(1))) void*)(bsrc[c] + db),
                (__attribute__((address_space(3))) void*)(&Bs[bsel][(wave * 4 + c) * 512]),
                16, 0, 0);
        }
    };

    auto mfma_tile = [&](int bsel) {
        const char* Ab = (const char*)As[bsel];
        const char* Bb = (const char*)Bs[bsel];
        #pragma unroll
        for (int kk = 0; kk < 2; ++kk) {
            int k0 = kk * 32;
            bh8 av[2], bv[4];
            #pragma unroll
            for (int mf = 0; mf < 2; ++mf) {
                unsigned row = (unsigned)(wm + mf * 16 + lr);
                unsigned bo = row * 128 + (unsigned)(k0 + lk) * 2;
                bo ^= (row & 7) << 4;
                av[mf] = *(const bh8*)(Ab + bo);
            }
            #pragma unroll
            for (int nf = 0; nf < 4; ++nf) {
                unsigned row = (unsigned)(wn + nf * 16 + lr);
                unsigned bo = row * 128 + (unsigned)(k0 + lk) * 2;
                bo ^= (row & 7) << 4;
                bv[nf] = *(const bh8*)(Bb + bo);
            }
            #pragma unroll
            for (int mf = 0; mf < 2; ++mf)
                #pragma unroll
                for (int nf = 0; nf < 4; ++nf)
                    acc[mf][nf] = __builtin_amdgcn_mfma_f32_16x16x32_bf16(av[mf], bv[nf], acc[mf][nf], 0, 0, 0);
        }
    };

    // prologue: 2 tiles in flight (12 loads/lane)
    stage(0, 0);
    stage(1, 1);

    for (int kt = 0; kt < 15; ++kt) {
        int bsel = kt & 1;
        asm volatile("s_waitcnt vmcnt(6)" ::: "memory");
        __builtin_amdgcn_s_barrier();
        asm volatile("" ::: "memory");
        mfma_tile(bsel);
        asm volatile("s_waitcnt lgkmcnt(0)" ::: "memory");
        __builtin_amdgcn_s_barrier();
        asm volatile("" ::: "memory");
        if (kt < 14) stage(kt + 2, bsel);
    }
    asm volatile("s_waitcnt vmcnt(0)" ::: "memory");
    __builtin_amdgcn_s_barrier();
    asm volatile("" ::: "memory");
    mfma_tile(1);

    if (use_pw) {
        #pragma unroll
        for (int mf = 0; mf < 2; ++mf) {
            #pragma unroll
            for (int rg = 0; rg < 4; ++rg) {
                int row = wm + mf * 16 + lg * 4 + rg;
                int p = plist[row];
                if (p < 0) continue;
                float wg = wl[row];
                #pragma unroll
                for (int nf = 0; nf < 4; ++nf) {
                    int r = wn + nf * 16 + lr;
                    pw[(size_t)p * RD + r] = f2bf(acc[mf][nf][rg] * wg);
                }
            }
        }
    } else {
        #pragma unroll
        for (int mf = 0; mf < 2; ++mf) {
            #pragma unroll
            for (int rg = 0; rg < 4; ++rg) {
                int row = wm + mf * 16 + lg * 4 + rg;
                int p = plist[row];
                if (p < 0) continue;
                float wg = wl[row];
                int t = p >> 3;
                #pragma unroll
                for (int nf = 0; nf < 4; ++nf) {
                    int r = wn + nf * 16 + lr;
                    atomicAdd(&outf[(size_t)t * RD + r], acc[mf][nf][rg] * wg);
                }
            }
        }
    }
}

// ---------------------------------------------------------------------------
// Kernel 6: y[t][r] = sum_k pw[(t*8+k)][r]   (pw path only; coalesced)
// ---------------------------------------------------------------------------
__global__ __launch_bounds__(256) void reduce_k(const unsigned short* __restrict__ pw,
                                                float* __restrict__ y) {
    int gid = blockIdx.x * 256 + threadIdx.x;
    int t = gid >> 7, r = gid & 127;
    float s = 0.f;
    #pragma unroll
    for (int k = 0; k < TOPK; ++k) {
        unsigned int w = ((unsigned int)pw[((size_t)t * TOPK + k) * RD + r]) << 16;
        s += __uint_as_float(w);
    }
    y[gid] = s;
}

// ---------------------------------------------------------------------------
extern "C" void kernel_launch(void* const* d_in, const int* in_sizes, int n_in,
                              void* d_out, int out_size, void* d_ws, size_t ws_size,
                              hipStream_t stream) {
    const float* x  = (const float*)d_in[0];
    const float* rw = (const float*)d_in[1];
    const float* nr = (const float*)d_in[2];
    float* out = (float*)d_out;
    char* ws = (char*)d_ws;
    int*    cnt   = (int*)(ws + CNT_OFF);
    int*    lists = (int*)(ws + LIST_OFF);
    int*    gcnt  = (int*)(ws + GC_OFF);
    __hip_bfloat16* nT = (__hip_bfloat16*)(ws + NT_OFF);
    double* sp    = (double*)(ws + NT_OFF);
    unsigned short* xbu = (unsigned short*)(ws + XB_OFF);
    unsigned short* pw  = (unsigned short*)(ws + PW_OFF);

    const int use_pw = (ws_size >= (size_t)PW_END) ? 1 : 0;

    if (!use_pw)
        hipMemsetAsync(out, 0, (size_t)NTOK * RD * sizeof(float), stream);
    score_k<<<1024, 256, 0, stream>>>(x, rw, sp, xbu);
    topk_k<<<NTOK / 4, 256, 0, stream>>>(sp, out);
    nt_cast<<<2048, 256, 0, stream>>>(nr, nT);
    hist_k<<<NHB, 256, 0, stream>>>(out, gcnt);
    scatter_k<<<NHB, 256, 0, stream>>>(out, gcnt, lists, cnt);
    gemm_k<<<NEXP * JM, 256, 0, stream>>>(xbu, (const unsigned short*)nT, cnt, lists, out, pw, use_pw);
    if (use_pw)
        reduce_k<<<(NTOK * RD) / 256, 256, 0, stream>>>(pw, out);
}

// Round 16
// 110.718 us; speedup vs baseline: 1.2660x; 1.0296x over previous
//
#include <hip/hip_runtime.h>
#include <hip/hip_bf16.h>
#include <stdint.h>

#define NTOK 8192
#define DIM  1024
#define RD   128
#define NEXP 64
#define TOPK 8
#define MAXT 4096
#define NHB  32    // histogram blocks (256 tokens each)
#define JM   32    // gemm j-range at M=64 (covers 2048 tokens/expert)

// d_out element offsets (f32 elements): output | weights | idx
#define W_OFF (NTOK * RD)            // 1048576
#define I_OFF (W_OFF + NTOK * TOPK)  // 1114112

// ws byte offsets
#define CNT_OFF  0
#define LIST_OFF 1024
#define GC_OFF   (LIST_OFF + NEXP * MAXT * 4)   // 1,049,600
#define NT_OFF   2360320
#define XB_OFF   (NT_OFF + (size_t)NEXP * RD * DIM * 2)    // 19,137,536
#define PW_OFF   (XB_OFF + (size_t)NTOK * DIM * 2)         // 35,914,752
#define PW_END   (PW_OFF + (size_t)NTOK * TOPK * RD * 2)   // 52,691,968
// NT region (16 MB) time-shared: sp f64 [4][NTOK][NEXP] during score/topk,
// then nT bf16 (nt_cast runs AFTER topk_k). XB: xb bf16 (fused x_cast).
// PW region (16 MB, bf16 partials) used ONLY if ws_size >= PW_END.

using bh8 = __attribute__((ext_vector_type(8))) short;
using fx4 = __attribute__((ext_vector_type(4))) float;
using dx2 = __attribute__((ext_vector_type(2))) double;
using dx4 = __attribute__((ext_vector_type(4))) double;

__device__ inline unsigned short f2bf(float f) {
    union { __hip_bfloat16 h; unsigned short u; } v;
    v.h = __float2bfloat16(f);
    return v.u;
}

// ---------------------------------------------------------------------------
// Kernel 0: neurons [e][d][r] f32  ->  nT [e][r][d] bf16  (B^T for MFMA)
// ---------------------------------------------------------------------------
__global__ __launch_bounds__(256) void nt_cast(const float* __restrict__ nr,
                                               __hip_bfloat16* __restrict__ nT) {
    int bx  = blockIdx.x;
    int e   = bx >> 5;
    int sub = bx & 31;
    int d0  = (sub >> 1) * 64;
    int r0  = (sub & 1) * 64;
    __shared__ float t[64][65];
    int tid = threadIdx.x;
    int dd  = tid >> 2;
    int rr4 = (tid & 3) * 16;
    const float* src = nr + ((size_t)e * DIM + d0 + dd) * RD + r0 + rr4;
    fx4 v[4];
    #pragma unroll
    for (int u = 0; u < 4; ++u) v[u] = ((const fx4*)src)[u];
    #pragma unroll
    for (int u = 0; u < 4; ++u)
        #pragma unroll
        for (int c = 0; c < 4; ++c) t[dd][rr4 + u * 4 + c] = v[u][c];
    __syncthreads();
    int rr  = tid >> 2;
    int dd4 = (tid & 3) * 16;
    union { unsigned short u[16]; uint4 q[2]; } o;
    #pragma unroll
    for (int i = 0; i < 16; ++i) o.u[i] = f2bf(t[dd4 + i][rr]);
    __hip_bfloat16* dst = nT + ((size_t)e * RD + r0 + rr) * DIM + d0 + dd4;
    ((uint4*)dst)[0] = o.q[0];
    ((uint4*)dst)[1] = o.q[1];
}

// ---------------------------------------------------------------------------
// Kernel 1: fp64 partial router scores, D-split x4 -> sp[ds][T][n]
// (r12-exact, measured 44.0 µs: f64 X+W LDS tiles, reg-prefetch,
// fused x_cast. sp bit-identical lineage.)
// ---------------------------------------------------------------------------
__global__ __launch_bounds__(256) void score_k(const float* __restrict__ x,
                                               const float* __restrict__ rw,
                                               double* __restrict__ sp,
                                               unsigned short* __restrict__ xb) {
    __shared__ __align__(16) char smem[2 * 64 * 66 * 8];   // 67,584 B
    double (*Xs)[66] = (double (*)[66])smem;
    double (*Ws)[66] = (double (*)[66])(smem + 64 * 66 * 8);
    double (*Ssc)[65] = (double (*)[65])smem;   // alias after compute

    int tid = threadIdx.x;
    int ds  = blockIdx.x & 3;
    int tb  = (blockIdx.x >> 2) * 64;
    int ni  = tid & 15;        // experts: ni + 16*j
    int ti  = tid >> 4;        // tokens:  ti*4 + i

    double acc[4][4];
    #pragma unroll
    for (int i = 0; i < 4; ++i)
        #pragma unroll
        for (int j = 0; j < 4; ++j) acc[i][j] = 0.0;

    int srow = tid >> 2;          // 0..63
    int scol = (tid & 3) * 16;    // 0,16,32,48

    fx4 xv[4], wv[4];
    {   // preload chunk 0
        const float* xs = x  + (size_t)(tb + srow) * DIM + ds * 256 + scol;
        const float* ws = rw + (size_t)srow        * DIM + ds * 256 + scol;
        #pragma unroll
        for (int u = 0; u < 4; ++u) { xv[u] = ((const fx4*)xs)[u]; wv[u] = ((const fx4*)ws)[u]; }
    }

    for (int c = 0; c < 4; ++c) {
        __syncthreads();   // prior dq-compute done reading LDS
        #pragma unroll
        for (int u = 0; u < 4; ++u) {
            #pragma unroll
            for (int k = 0; k < 4; k += 2) {
                dx2 xd; xd[0] = (double)xv[u][k]; xd[1] = (double)xv[u][k + 1];
                *(dx2*)&Xs[srow][scol + u * 4 + k] = xd;
                dx2 wd; wd[0] = (double)wv[u][k]; wd[1] = (double)wv[u][k + 1];
                *(dx2*)&Ws[srow][scol + u * 4 + k] = wd;
            }
        }
        // fused x_cast
        {
            bh8 o0, o1;
            #pragma unroll
            for (int c2 = 0; c2 < 4; ++c2) {
                o0[c2]     = (short)f2bf(xv[0][c2]);
                o0[4 + c2] = (short)f2bf(xv[1][c2]);
                o1[c2]     = (short)f2bf(xv[2][c2]);
                o1[4 + c2] = (short)f2bf(xv[3][c2]);
            }
            unsigned short* xd = xb + (size_t)(tb + srow) * DIM + ds * 256 + c * 64 + scol;
            *(bh8*)xd = o0;
            *(bh8*)(xd + 8) = o1;
        }
        __syncthreads();
        if (c < 3) {   // prefetch next chunk
            int d0 = ds * 256 + (c + 1) * 64;
            const float* xs = x  + (size_t)(tb + srow) * DIM + d0 + scol;
            const float* ws = rw + (size_t)srow        * DIM + d0 + scol;
            #pragma unroll
            for (int u = 0; u < 4; ++u) { xv[u] = ((const fx4*)xs)[u]; wv[u] = ((const fx4*)ws)[u]; }
        }
        for (int dq = 0; dq < 64; dq += 4) {
            dx4 xa[4], wb[4];
            #pragma unroll
            for (int i = 0; i < 4; ++i) xa[i] = *(const dx4*)&Xs[ti * 4 + i][dq];
            #pragma unroll
            for (int j = 0; j < 4; ++j) wb[j] = *(const dx4*)&Ws[ni + 16 * j][dq];
            #pragma unroll
            for (int i = 0; i < 4; ++i)
                #pragma unroll
                for (int j = 0; j < 4; ++j)
                    acc[i][j] += xa[i][0] * wb[j][0]
                               + xa[i][1] * wb[j][1]
                               + xa[i][2] * wb[j][2]
                               + xa[i][3] * wb[j][3];
        }
    }
    __syncthreads();
    #pragma unroll
    for (int i = 0; i < 4; ++i)
        #pragma unroll
        for (int j = 0; j < 4; ++j) Ssc[ti * 4 + i][ni + 16 * j] = acc[i][j];
    __syncthreads();

    int t  = tid >> 2;
    int n0 = (tid & 3) * 16;
    double* dst = sp + ((size_t)ds * NTOK + tb + t) * NEXP + n0;
    #pragma unroll
    for (int k = 0; k < 16; ++k) dst[k] = Ssc[t][n0 + k];
}

// ---------------------------------------------------------------------------
// Kernel 2: wave-per-token f64 top-8 + softmax. Plain stores only.
// ---------------------------------------------------------------------------
__global__ __launch_bounds__(256) void topk_k(const double* __restrict__ sp,
                                              float* __restrict__ out) {
    int wave = threadIdx.x >> 6, lane = threadIdx.x & 63;
    int T = blockIdx.x * 4 + wave;

    const double* base = sp + (size_t)T * NEXP + lane;
    const size_t SL = (size_t)NTOK * NEXP;
    double s = base[0] + base[SL] + base[2 * SL] + base[3 * SL];

    double vals[TOPK]; int idxs[TOPK];
    double cur = s;
    #pragma unroll
    for (int p = 0; p < TOPK; ++p) {
        double v = cur; int i = lane;
        #pragma unroll
        for (int off = 32; off > 0; off >>= 1) {
            double ov = __shfl_xor(v, off, 64);
            int    oi = __shfl_xor(i, off, 64);
            if (ov > v || (ov == v && oi < i)) { v = ov; i = oi; }
        }
        vals[p] = v; idxs[p] = i;
        if (lane == i) cur = -1e300;
    }

    double m = vals[0], sum = 0.0, ex[TOPK];
    #pragma unroll
    for (int p = 0; p < TOPK; ++p) { ex[p] = exp(vals[p] - m); sum += ex[p]; }
    double inv = 1.0 / sum;

    if (lane < TOPK) {
        int p = lane;
        out[W_OFF + T * TOPK + p] = (float)(ex[p] * inv);
        out[I_OFF + T * TOPK + p] = (float)idxs[p];
    }
}

// ---------------------------------------------------------------------------
// Kernel 3: per-block expert histogram (LDS atomics only)
// ---------------------------------------------------------------------------
__global__ __launch_bounds__(256) void hist_k(const float* __restrict__ out,
                                              int* __restrict__ gcnt) {
    __shared__ int lh[NEXP];
    int tid = threadIdx.x;
    if (tid < NEXP) lh[tid] = 0;
    __syncthreads();
    int T = blockIdx.x * 256 + tid;
    const fx4* ip = (const fx4*)(out + I_OFF + (size_t)T * TOPK);
    fx4 a = ip[0], b = ip[1];
    #pragma unroll
    for (int p = 0; p < 4; ++p) { atomicAdd(&lh[(int)a[p]], 1); atomicAdd(&lh[(int)b[p]], 1); }
    __syncthreads();
    if (tid < NEXP) gcnt[blockIdx.x * NEXP + tid] = lh[tid];
}

// ---------------------------------------------------------------------------
// Kernel 4: scatter entries into lists (scan folded in, r14/r15-validated:
// each block computes its prefix from gcnt; block 0 writes cnt totals)
// ---------------------------------------------------------------------------
__global__ __launch_bounds__(256) void scatter_k(const float* __restrict__ out,
                                                 const int* __restrict__ gcnt,
                                                 int* __restrict__ lists,
                                                 int* __restrict__ cnt) {
    __shared__ int lh[NEXP];
    __shared__ int bo[NEXP];
    int tid = threadIdx.x;
    if (tid < NEXP) {
        lh[tid] = 0;
        int s = 0, tot = 0;
        #pragma unroll
        for (int b = 0; b < NHB; ++b) {
            int g = gcnt[b * NEXP + tid];
            if (b < (int)blockIdx.x) s += g;
            tot += g;
        }
        bo[tid] = tid * MAXT + s;
        if (blockIdx.x == 0) cnt[tid] = tot;
    }
    __syncthreads();
    int T = blockIdx.x * 256 + tid;
    const fx4* ip = (const fx4*)(out + I_OFF + (size_t)T * TOPK);
    fx4 a = ip[0], b = ip[1];
    int ev[TOPK] = {(int)a[0], (int)a[1], (int)a[2], (int)a[3],
                    (int)b[0], (int)b[1], (int)b[2], (int)b[3]};
    #pragma unroll
    for (int p = 0; p < TOPK; ++p) {
        int e = ev[p];
        int pos = atomicAdd(&lh[e], 1);
        lists[bo[e] + pos] = (T << 3) | p;
    }
}

// ---------------------------------------------------------------------------
// Kernel 5: grouped gather-GEMM, tile 64 tok x 128 R, BK=64, depth-2
// counted-vmcnt pipeline (r12 structure, best known).
// ---------------------------------------------------------------------------
__global__ __launch_bounds__(256) void gemm_k(const unsigned short* __restrict__ xb,
                                              const unsigned short* __restrict__ nTb,
                                              const int* __restrict__ cnt,
                                              const int* __restrict__ lists,
                                              float* __restrict__ outf,
                                              unsigned short* __restrict__ pw,
                                              int use_pw) {
    int e = blockIdx.x & 63;
    int j = blockIdx.x >> 6;       // 0..JM-1
    int ce = cnt[e];
    int base = j * 64;
    if (base >= ce) return;

    __shared__ unsigned short As[2][64 * 64];    // 16 KB
    __shared__ unsigned short Bs[2][128 * 64];   // 32 KB
    __shared__ int   plist[64];
    __shared__ float wl[64];

    int tid = threadIdx.x;
    int wave = tid >> 6, lane = tid & 63;
    if (tid < 64) {
        int idx = base + tid;
        int p = (idx < ce) ? lists[e * MAXT + idx] : -1;
        plist[tid] = p;
        wl[tid] = (p >= 0) ? outf[W_OFF + p] : 0.0f;
    }
    __syncthreads();

    fx4 acc[2][4];
    #pragma unroll
    for (int a = 0; a < 2; ++a)
        #pragma unroll
        for (int b = 0; b < 4; ++b) acc[a][b] = (fx4){0.f, 0.f, 0.f, 0.f};

    unsigned soff = 16u * (unsigned)((lane & 7) ^ (lane >> 3));
    const char* asrc[2];
    const char* bsrc[4];
    const char* xbb = (const char*)xb;
    const char* ntb = (const char*)(nTb + (size_t)e * RD * DIM);
    #pragma unroll
    for (int c = 0; c < 2; ++c) {
        int row = (wave * 2 + c) * 8 + (lane >> 3);   // 0..63
        int p = plist[row];
        int tok = (p < 0) ? 0 : (p >> 3);
        asrc[c] = xbb + (size_t)tok * (DIM * 2) + soff;
    }
    #pragma unroll
    for (int c = 0; c < 4; ++c) {
        int row = (wave * 4 + c) * 8 + (lane >> 3);   // 0..127
        bsrc[c] = ntb + (size_t)row * (DIM * 2) + soff;
    }

    int wm = (wave >> 1) * 32, wn = (wave & 1) * 64;
    int lr = lane & 15, lk = (lane >> 4) * 8;
    int lg = lane >> 4;

    auto stage = [&](int kt, int bsel) {
        int db = kt * 128;
        #pragma unroll
        for (int c = 0; c < 2; ++c) {
            __builtin_amdgcn_global_load_lds(
                (const __attribute__((address_space(1))) void*)(asrc[c] + db),
                (__attribute__((address_space(3))) void*)(&As[bsel][(wave * 2 + c) * 512]),
                16, 0, 0);
        }
        #pragma unroll
        for (int c = 0; c < 4; ++c) {
            __builtin_amdgcn_global_load_lds(
                (const __attribute__((address_space(1))) void*)(bsrc[c] + db),
                (__attribute__((address_space(3))) void*)(&Bs[bsel][(wave * 4 + c) * 512]),
                16, 0, 0);
        }
    };

    auto mfma_tile = [&](int bsel) {
        const char* Ab = (const char*)As[bsel];
        const char* Bb = (const char*)Bs[bsel];
        #pragma unroll
        for (int kk = 0; kk < 2; ++kk) {
            int k0 = kk * 32;
            bh8 av[2], bv[4];
            #pragma unroll
            for (int mf = 0; mf < 2; ++mf) {
                unsigned row = (unsigned)(wm + mf * 16 + lr);
                unsigned bo = row * 128 + (unsigned)(k0 + lk) * 2;
                bo ^= (row & 7) << 4;
                av[mf] = *(const bh8*)(Ab + bo);
            }
            #pragma unroll
            for (int nf = 0; nf < 4; ++nf) {
                unsigned row = (unsigned)(wn + nf * 16 + lr);
                unsigned bo = row * 128 + (unsigned)(k0 + lk) * 2;
                bo ^= (row & 7) << 4;
                bv[nf] = *(const bh8*)(Bb + bo);
            }
            #pragma unroll
            for (int mf = 0; mf < 2; ++mf)
                #pragma unroll
                for (int nf = 0; nf < 4; ++nf)
                    acc[mf][nf] = __builtin_amdgcn_mfma_f32_16x16x32_bf16(av[mf], bv[nf], acc[mf][nf], 0, 0, 0);
        }
    };

    // prologue: 2 tiles in flight (12 loads/lane)
    stage(0, 0);
    stage(1, 1);

    for (int kt = 0; kt < 15; ++kt) {
        int bsel = kt & 1;
        asm volatile("s_waitcnt vmcnt(6)" ::: "memory");
        __builtin_amdgcn_s_barrier();
        asm volatile("" ::: "memory");
        mfma_tile(bsel);
        asm volatile("s_waitcnt lgkmcnt(0)" ::: "memory");
        __builtin_amdgcn_s_barrier();
        asm volatile("" ::: "memory");
        if (kt < 14) stage(kt + 2, bsel);
    }
    asm volatile("s_waitcnt vmcnt(0)" ::: "memory");
    __builtin_amdgcn_s_barrier();
    asm volatile("" ::: "memory");
    mfma_tile(1);

    if (use_pw) {
        #pragma unroll
        for (int mf = 0; mf < 2; ++mf) {
            #pragma unroll
            for (int rg = 0; rg < 4; ++rg) {
                int row = wm + mf * 16 + lg * 4 + rg;
                int p = plist[row];
                if (p < 0) continue;
                float wg = wl[row];
                #pragma unroll
                for (int nf = 0; nf < 4; ++nf) {
                    int r = wn + nf * 16 + lr;
                    pw[(size_t)p * RD + r] = f2bf(acc[mf][nf][rg] * wg);
                }
            }
        }
    } else {
        #pragma unroll
        for (int mf = 0; mf < 2; ++mf) {
            #pragma unroll
            for (int rg = 0; rg < 4; ++rg) {
                int row = wm + mf * 16 + lg * 4 + rg;
                int p = plist[row];
                if (p < 0) continue;
                float wg = wl[row];
                int t = p >> 3;
                #pragma unroll
                for (int nf = 0; nf < 4; ++nf) {
                    int r = wn + nf * 16 + lr;
                    atomicAdd(&outf[(size_t)t * RD + r], acc[mf][nf][rg] * wg);
                }
            }
        }
    }
}

// ---------------------------------------------------------------------------
// Kernel 6: y[t][r] = sum_k pw[(t*8+k)][r]   (pw path only; coalesced)
// ---------------------------------------------------------------------------
__global__ __launch_bounds__(256) void reduce_k(const unsigned short* __restrict__ pw,
                                                float* __restrict__ y) {
    int gid = blockIdx.x * 256 + threadIdx.x;
    int t = gid >> 7, r = gid & 127;
    float s = 0.f;
    #pragma unroll
    for (int k = 0; k < TOPK; ++k) {
        unsigned int w = ((unsigned int)pw[((size_t)t * TOPK + k) * RD + r]) << 16;
        s += __uint_as_float(w);
    }
    y[gid] = s;
}

// ---------------------------------------------------------------------------
extern "C" void kernel_launch(void* const* d_in, const int* in_sizes, int n_in,
                              void* d_out, int out_size, void* d_ws, size_t ws_size,
                              hipStream_t stream) {
    const float* x  = (const float*)d_in[0];
    const float* rw = (const float*)d_in[1];
    const float* nr = (const float*)d_in[2];
    float* out = (float*)d_out;
    char* ws = (char*)d_ws;
    int*    cnt   = (int*)(ws + CNT_OFF);
    int*    lists = (int*)(ws + LIST_OFF);
    int*    gcnt  = (int*)(ws + GC_OFF);
    __hip_bfloat16* nT = (__hip_bfloat16*)(ws + NT_OFF);
    double* sp    = (double*)(ws + NT_OFF);
    unsigned short* xbu = (unsigned short*)(ws + XB_OFF);
    unsigned short* pw  = (unsigned short*)(ws + PW_OFF);

    const int use_pw = (ws_size >= (size_t)PW_END) ? 1 : 0;

    if (!use_pw)
        hipMemsetAsync(out, 0, (size_t)NTOK * RD * sizeof(float), stream);
    score_k<<<512, 256, 0, stream>>>(x, rw, sp, xbu);
    topk_k<<<NTOK / 4, 256, 0, stream>>>(sp, out);
    nt_cast<<<2048, 256, 0, stream>>>(nr, nT);
    hist_k<<<NHB, 256, 0, stream>>>(out, gcnt);
    scatter_k<<<NHB, 256, 0, stream>>>(out, gcnt, lists, cnt);
    gemm_k<<<NEXP * JM, 256, 0, stream>>>(xbu, (const unsigned short*)nT, cnt, lists, out, pw, use_pw);
    if (use_pw)
        reduce_k<<<(NTOK * RD) / 256, 256, 0, stream>>>(pw, out);
}